// Round 14
// baseline (75.090 us; speedup 1.0000x reference)
//
#include <hip/hip_runtime.h>
#include <math.h>

#define Bn 16
#define Ln 1444      // 38*38
#define NCn 21
#define Cn 64
#define NBn 23       // 64-position tiles
#define KC 1344      // 21*64
#define NG 336       // KC/4

// ---- Kernel B: unchanged from R13 (passing) -------------------------------
__global__ __launch_bounds__(256) void kB(const float* __restrict__ cls_pred,
                                          const float* __restrict__ source,
                                          const float* __restrict__ R,
                                          int* __restrict__ cls_idx,
                                          float* __restrict__ src_out,
                                          float* __restrict__ bs,
                                          float2* __restrict__ Gg) {
    int b = blockIdx.x & 15, m = blockIdx.x >> 4;
    int base = m * 64;
    int lane = threadIdx.x & 63, grp = threadIdx.x >> 6;
    __shared__ float sh[9536];
    __shared__ int cls[64];
    float (*tile)[65] = (float(*)[65])sh;
    float* clsP = sh + 4160;
    float* WS   = sh + 4160;

    if (blockIdx.x == 0) {
        for (int i = threadIdx.x; i < 441; i += 256) {
            int a = i / 21, k = i % 21;
            float rak = R[a * 21 + k], rka = R[k * 21 + a];
            Gg[i] = make_float2(rak - rka, rka);
        }
    }

#pragma unroll
    for (int cc = 0; cc < 16; cc++) {
        int c = grp * 16 + cc;
        float v = 0.f;
        if (base + lane < Ln) v = source[((size_t)b * Cn + c) * Ln + base + lane];
        tile[c][lane] = v;
    }
    {
        const float4* gp = reinterpret_cast<const float4*>(cls_pred + ((size_t)b * Ln + base) * 84);
        int lim4 = (Ln - base) * 21;
#pragma unroll
        for (int it = 0; it < 6; it++) {
            int f4 = threadIdx.x + it * 256;
            if (f4 < 1344) {
                float4 v = (f4 < lim4) ? gp[f4] : make_float4(0.f, 0.f, 0.f, 0.f);
                reinterpret_cast<float4*>(clsP)[f4] = v;
            }
        }
    }
    __syncthreads();

    {
        int p = threadIdx.x >> 2, a = threadIdx.x & 3;
        bool valid = (base + p < Ln);
        const float* q = clsP + p * 84 + a * 21;
        float x[21];
#pragma unroll
        for (int i = 0; i < 21; i++) x[i] = q[i];
        float mx = x[0];
#pragma unroll
        for (int i = 1; i < 21; i++) mx = fmaxf(mx, x[i]);
        float s = 0.f;
#pragma unroll
        for (int i = 0; i < 21; i++) { x[i] = expf(x[i] - mx); s += x[i]; }
        float best = -1.f; int bi = 0;
#pragma unroll
        for (int i = 0; i < 21; i++) {
            float sm = x[i] / s;
            if (sm > best) { best = sm; bi = a * 21 + i; }
        }
#pragma unroll
        for (int d = 1; d <= 2; d <<= 1) {
            float ob = __shfl_xor(best, d);
            int oi = __shfl_xor(bi, d);
            if (ob > best || (ob == best && oi < bi)) { best = ob; bi = oi; }
        }
        if (a == 0) {
            if (valid) { int k = bi % 21; cls[p] = k; cls_idx[b * Ln + base + p] = k; }
            else cls[p] = 255;
        }
    }
    __syncthreads();

    float cs[21];
#pragma unroll
    for (int k = 0; k < 21; k++) cs[k] = 0.f;
#pragma unroll
    for (int jj = 0; jj < 16; jj++) {
        int j = grp * 16 + jj;
        float v = tile[lane][j];
        if (base + j < Ln) src_out[((size_t)b * Ln + base + j) * Cn + lane] = v;
        int k = cls[j];
#pragma unroll
        for (int kk = 0; kk < 21; kk++) cs[kk] += (kk == k) ? v : 0.f;
    }
#pragma unroll
    for (int kk = 0; kk < 21; kk++) WS[grp * KC + kk * 64 + lane] = cs[kk];
    __syncthreads();

    for (int i = threadIdx.x; i < KC; i += 256) {
        float v = WS[i] + WS[KC + i] + WS[2 * KC + i] + WS[3 * KC + i];
        bs[((size_t)b * NBn + m) * KC + i] = v;
    }
}

// ---- kCm<AS,AL>: R13 kC with stream amplified xAS, LDS phases xAL ---------
template<int AS, int AL>
__global__ __launch_bounds__(512, 2) void kCm(const float* __restrict__ src,
                                              const int* __restrict__ cls_idx,
                                              const float2* __restrict__ Gg,
                                              const float* __restrict__ bs,
                                              float* __restrict__ fused) {
    int b = blockIdx.x & 15, m = blockIdx.x >> 4;
    int base = m * 64;
    int lane = threadIdx.x & 63, grp = threadIdx.x >> 6;
    __shared__ float PS[KC];
    __shared__ float Tt[KC];
    __shared__ float WS[8][KC];
    __shared__ int cls[64];

    volatile int zv = 0;
    int z = zv;                               // runtime 0, opaque to optimizer

    float sT[8];
#pragma unroll
    for (int t = 0; t < 8; t++) {
        int i = grp * 8 + t;
        sT[t] = (base + i < Ln) ? src[((size_t)b * Ln + base + i) * Cn + lane] : 0.f;
    }
    if (threadIdx.x < 64) {
        int k = 0;
        if (base + (int)threadIdx.x < Ln) k = cls_idx[b * Ln + base + threadIdx.x];
        cls[threadIdx.x] = k;
    }
    // stream phase (amplified AS): z*rep = 0 at runtime, defeats load hoisting
    if (threadIdx.x < NG) {
        int g = threadIdx.x;
        for (int rep = 0; rep < AS; rep++) {
            const float4* pp = reinterpret_cast<const float4*>(bs)
                               + (size_t)b * NBn * NG + g + (size_t)(z * rep);
            float rx = 0.f, ry = 0.f, rz = 0.f, rw = 0.f;
            float px = 0.f, py = 0.f, pz = 0.f, pw = 0.f;
#pragma unroll
            for (int mm = 0; mm < NBn; mm++) {
                float4 v = pp[(size_t)mm * NG];
                rx += v.x; ry += v.y; rz += v.z; rw += v.w;
                if (mm < m) { px += v.x; py += v.y; pz += v.z; pw += v.w; }
            }
            PS[g * 4] = px; PS[g * 4 + 1] = py; PS[g * 4 + 2] = pz; PS[g * 4 + 3] = pw;
            Tt[g * 4] = rx; Tt[g * 4 + 1] = ry; Tt[g * 4 + 2] = rz; Tt[g * 4 + 3] = rw;
        }
    }
    __syncthreads();   // S1

    int cj[8];
#pragma unroll
    for (int j = 0; j < 8; j++) cj[j] = cls[grp * 8 + j];

    float cs[21];
#pragma unroll
    for (int k = 0; k < 21; k++) cs[k] = 0.f;
#pragma unroll
    for (int t = 0; t < 8; t++) {
        int k = cj[t];
#pragma unroll
        for (int kk = 0; kk < 21; kk++) cs[kk] += (kk == k) ? sT[t] : 0.f;
    }

    // LDS phases (amplified AL): WS write -> prefix -> msW/Tc read
    float Tc[21], msW[21];
    for (int rep = 0; rep < AL; rep++) {
#pragma unroll
        for (int kk = 0; kk < 21; kk++) WS[grp][kk * 64 + lane] = cs[kk];
        __syncthreads();   // rows complete
        for (int i = threadIdx.x; i < KC; i += 512) {
            float run = PS[i];
#pragma unroll
            for (int g = 0; g < 8; g++) {
                float w = WS[g][i];
                WS[g][i] = run;
                run += w;
            }
        }
        __syncthreads();   // prefix done
#pragma unroll
        for (int k = 0; k < 21; k++) Tc[k] = Tt[k * 64 + lane];
#pragma unroll
        for (int k = 0; k < 21; k++) msW[k] = WS[grp][k * 64 + lane];
        {
            float sink = 0.f;
#pragma unroll
            for (int k = 0; k < 21; k++) sink += msW[k] + Tc[k];
            asm volatile("" :: "v"(sink));   // keep mid-rep reads live (rule #17)
        }
        __syncthreads();   // protect WS before next rep's overwrite
    }

    // final combine (R13 scalar-Q version, once)
    int nvalid = (Ln - base < 64) ? (Ln - base) : 64;
#pragma unroll
    for (int t = 0; t < 8; t++) {
        int i = grp * 8 + t;
        if (i < nvalid) {
            int cis = __builtin_amdgcn_readfirstlane(cj[t]);
            const float2* grow = Gg + cis * 21;
            float sv = sT[t];
            float accA = (((cis != 0) ? 1.f : 0.f) - grow[cis].y) * sv;
            float accB = 0.f;
#pragma unroll
            for (int k = 0; k < 21; k++) {
                float2 w = grow[k];
                accA = fmaf(w.x, msW[k], accA);
                accB = fmaf(w.y, Tc[k], accB);
            }
#pragma unroll
            for (int j = 0; j < 8; j++)
                if (j < t) {
                    int cjs = __builtin_amdgcn_readfirstlane(cj[j]);
                    accA = fmaf(grow[cjs].x, sT[j], accA);
                }
            fused[((size_t)b * Ln + base + i) * Cn + lane] = accA + accB;
        }
    }
}

extern "C" void kernel_launch(void* const* d_in, const int* in_sizes, int n_in,
                              void* d_out, int out_size, void* d_ws, size_t ws_size,
                              hipStream_t stream) {
    const float* cls_pred = (const float*)d_in[0];
    const float* source = (const float*)d_in[1];
    const float* cls_r_prob = (const float*)d_in[2];

    float* fused = (float*)d_out;
    float* src_out = fused + (size_t)Bn * Ln * Cn;

    char* w = (char*)d_ws;
    int* cls_idx = (int*)w;
    size_t off = ((size_t)Bn * Ln * 4 + 1023) & ~(size_t)1023;
    float* bs = (float*)(w + off);
    float2* Gg = (float2*)(w + off + (size_t)Bn * NBn * KC * 4);

    hipLaunchKernelGGL(kB, dim3(Bn * NBn), dim3(256), 0, stream,
                       cls_pred, source, cls_r_prob, cls_idx, src_out, bs, Gg);
    hipLaunchKernelGGL((kCm<16, 1>), dim3(Bn * NBn), dim3(512), 0, stream,
                       src_out, cls_idx, Gg, bs, fused);
    hipLaunchKernelGGL((kCm<1, 16>), dim3(Bn * NBn), dim3(512), 0, stream,
                       src_out, cls_idx, Gg, bs, fused);
}

// Round 15
// 31.653 us; speedup vs baseline: 2.3723x; 2.3723x over previous
//
#include <hip/hip_runtime.h>
#include <math.h>

#define Bn 16
#define Ln 1444      // 38*38
#define NCn 21
#define Cn 64
#define NBn 23       // 64-position tiles
#define KC 1344      // 21*64
#define NG 336       // KC/4

// ---- Kernel B: classify + transpose + tile class sums + LOCAL combine -----
// 512 threads / 8 waves. XCD-local: b=bid&15, m=bid>>4.
// LDS: tile[64][65] 16640B + WSb[8*KC] 43008B (clsP overlays) + cls 256B = ~59.9KB
__global__ __launch_bounds__(512, 2) void kB(const float* __restrict__ cls_pred,
                                             const float* __restrict__ source,
                                             const float* __restrict__ R,
                                             int* __restrict__ cls_idx,
                                             float* __restrict__ src_out,
                                             float* __restrict__ bs,
                                             float* __restrict__ fused) {
    int b = blockIdx.x & 15, m = blockIdx.x >> 4;
    int base = m * 64;
    int lane = threadIdx.x & 63, grp = threadIdx.x >> 6;   // 8 waves, 8 pos each
    __shared__ float tile[64][65];
    __shared__ float WSb[8 * KC];
    __shared__ int cls[64];
    float* clsP = WSb;                    // 5376 floats, dead after classify

    // stage tile: wave grp loads channel rows grp*8..+7 (coalesced)
#pragma unroll
    for (int cc = 0; cc < 8; cc++) {
        int c = grp * 8 + cc;
        float v = 0.f;
        if (base + lane < Ln) v = source[((size_t)b * Cn + c) * Ln + base + lane];
        tile[c][lane] = v;
    }
    // stage cls_pred tile (coalesced float4)
    {
        const float4* gp = reinterpret_cast<const float4*>(cls_pred + ((size_t)b * Ln + base) * 84);
        int lim4 = (Ln - base) * 21;
#pragma unroll
        for (int it = 0; it < 3; it++) {
            int f4 = threadIdx.x + it * 512;
            if (f4 < 1344) {
                float4 v = (f4 < lim4) ? gp[f4] : make_float4(0.f, 0.f, 0.f, 0.f);
                reinterpret_cast<float4*>(clsP)[f4] = v;
            }
        }
    }
    __syncthreads();   // S1: tile + clsP ready

    if (threadIdx.x < 256) {
        // waves 0-3: classify (math identical to passing R13)
        int p = threadIdx.x >> 2, a = threadIdx.x & 3;
        bool valid = (base + p < Ln);
        const float* q = clsP + p * 84 + a * 21;
        float x[21];
#pragma unroll
        for (int i = 0; i < 21; i++) x[i] = q[i];
        float mx = x[0];
#pragma unroll
        for (int i = 1; i < 21; i++) mx = fmaxf(mx, x[i]);
        float s = 0.f;
#pragma unroll
        for (int i = 0; i < 21; i++) { x[i] = expf(x[i] - mx); s += x[i]; }
        float best = -1.f; int bi = 0;
#pragma unroll
        for (int i = 0; i < 21; i++) {
            float sm = x[i] / s;                     // exact per-element division (matches ref)
            if (sm > best) { best = sm; bi = a * 21 + i; }
        }
#pragma unroll
        for (int d = 1; d <= 2; d <<= 1) {
            float ob = __shfl_xor(best, d);
            int oi = __shfl_xor(bi, d);
            if (ob > best || (ob == best && oi < bi)) { best = ob; bi = oi; }
        }
        if (a == 0) {
            if (valid) { int k = bi % 21; cls[p] = k; cls_idx[b * Ln + base + p] = k; }
            else cls[p] = 255;
        }
    } else {
        // waves 4-7: overlap the src_out write (needs only tile)
        int g2 = grp - 4;                            // 0..3, 16 positions each
#pragma unroll
        for (int jj = 0; jj < 16; jj++) {
            int j = g2 * 16 + jj;
            if (base + j < Ln) src_out[((size_t)b * Ln + base + j) * Cn + lane] = tile[lane][j];
        }
    }
    __syncthreads();   // S2: cls ready, clsP dead (WSb may be written)

    // per-wave class sums over own 8 positions (registers)
    int cj[8]; float sT[8];
#pragma unroll
    for (int t = 0; t < 8; t++) {
        cj[t] = cls[grp * 8 + t];
        sT[t] = tile[lane][grp * 8 + t];             // 2-way bank alias: free
    }
    {
        float cs[21];
#pragma unroll
        for (int k = 0; k < 21; k++) cs[k] = 0.f;
#pragma unroll
        for (int t = 0; t < 8; t++) {
            int k = cj[t];
#pragma unroll
            for (int kk = 0; kk < 21; kk++) cs[kk] += (kk == k) ? sT[t] : 0.f;
        }
#pragma unroll
        for (int kk = 0; kk < 21; kk++) WSb[grp * KC + kk * 64 + lane] = cs[kk];
    }
    __syncthreads();   // S3: WSb rows complete

    // cooperative exclusive prefix over 8 wave rows; row-total -> bs
    for (int i = threadIdx.x; i < KC; i += 512) {
        float run = 0.f;
#pragma unroll
        for (int g = 0; g < 8; g++) {
            float w = WSb[g * KC + i];
            WSb[g * KC + i] = run;
            run += w;
        }
        bs[((size_t)b * NBn + m) * KC + i] = run;    // tile totals
    }
    __syncthreads();   // S4: WSb[g] = intra-tile class prefix before wave g

    // LOCAL combine: diag + Gx*ms_intra + within-wave triangular -> fused
    float msW[21];
#pragma unroll
    for (int k = 0; k < 21; k++) msW[k] = WSb[grp * KC + k * 64 + lane];
    int nvalid = (Ln - base < 64) ? (Ln - base) : 64;
#pragma unroll
    for (int t = 0; t < 8; t++) {
        int i = grp * 8 + t;
        if (i < nvalid) {                            // wave-uniform
            int cis = __builtin_amdgcn_readfirstlane(cj[t]);
            const float* rrow = R + cis * 21;        // R[cis][k], scalar loads
            float sv = sT[t];
            float acc = (((cis != 0) ? 1.f : 0.f) - rrow[cis]) * sv;
#pragma unroll
            for (int k = 0; k < 21; k++)
                acc = fmaf(rrow[k] - R[k * 21 + cis], msW[k], acc);   // Gx = R[a,k]-R[k,a]
#pragma unroll
            for (int j = 0; j < 8; j++)              // triangular j < t
                if (j < t) {
                    int cjs = __builtin_amdgcn_readfirstlane(cj[j]);
                    acc = fmaf(rrow[cjs] - R[cjs * 21 + cis], sT[j], acc);
                }
            fused[((size_t)b * Ln + base + i) * Cn + lane] = acc;
        }
    }
}

// ---- Kernel C: bs stream -> PS/Tt, U[21][64] build, fused += U[ci] --------
// LDS ~16.4 KB -> 4 blocks/CU. Same XCD-local mapping -> RMW is L2-hit.
__global__ __launch_bounds__(512) void kC(const int* __restrict__ cls_idx,
                                          const float* __restrict__ R,
                                          const float* __restrict__ bs,
                                          float* __restrict__ fused) {
    int b = blockIdx.x & 15, m = blockIdx.x >> 4;
    int base = m * 64;
    int lane = threadIdx.x & 63, grp = threadIdx.x >> 6;
    __shared__ float PS[KC];       // prefix over tiles < m
    __shared__ float Tt[KC];       // batch totals
    __shared__ float U[KC];        // U[a*64+c]
    __shared__ int cls[64];

    // stream bs: threads 0..335 own one float4 group, 23 batched loads (L2-local)
    if (threadIdx.x < NG) {
        int g = threadIdx.x;
        float rx = 0.f, ry = 0.f, rz = 0.f, rw = 0.f;
        float px = 0.f, py = 0.f, pz = 0.f, pw = 0.f;
#pragma unroll
        for (int mm = 0; mm < NBn; mm++) {
            float4 v = *reinterpret_cast<const float4*>(&bs[((size_t)b * NBn + mm) * KC + g * 4]);
            rx += v.x; ry += v.y; rz += v.z; rw += v.w;
            if (mm < m) { px += v.x; py += v.y; pz += v.z; pw += v.w; }  // uniform branch
        }
        PS[g * 4] = px; PS[g * 4 + 1] = py; PS[g * 4 + 2] = pz; PS[g * 4 + 3] = pw;
        Tt[g * 4] = rx; Tt[g * 4 + 1] = ry; Tt[g * 4 + 2] = rz; Tt[g * 4 + 3] = rw;
    }
    if (threadIdx.x < 64) {
        int k = 0;
        if (base + (int)threadIdx.x < Ln) k = cls_idx[b * Ln + base + threadIdx.x];
        cls[threadIdx.x] = k;
    }
    __syncthreads();   // S1: PS/Tt/cls ready

    // U[a][c] = sum_k Gx[a,k]*PS[k,c] + Gy[a,k]*Tt[k,c]; a wave-uniform
    for (int a = grp; a < 21; a += 8) {
        const float* rrow = R + a * 21;              // scalar loads
        float acc = 0.f;
#pragma unroll
        for (int k = 0; k < 21; k++) {
            float rak = rrow[k], rka = R[k * 21 + a];
            acc = fmaf(rak - rka, PS[k * 64 + lane], acc);
            acc = fmaf(rka, Tt[k * 64 + lane], acc);
        }
        U[a * 64 + lane] = acc;
    }
    __syncthreads();   // S2: U ready

    // fused += U[ci] over own 8 positions (read-modify-write, L2-local)
    int nvalid = (Ln - base < 64) ? (Ln - base) : 64;
#pragma unroll
    for (int t = 0; t < 8; t++) {
        int i = grp * 8 + t;
        if (i < nvalid) {
            int ci = cls[i];                         // wave-uniform broadcast
            size_t o = ((size_t)b * Ln + base + i) * Cn + lane;
            fused[o] += U[ci * 64 + lane];           // conflict-free (2-way)
        }
    }
}

extern "C" void kernel_launch(void* const* d_in, const int* in_sizes, int n_in,
                              void* d_out, int out_size, void* d_ws, size_t ws_size,
                              hipStream_t stream) {
    const float* cls_pred = (const float*)d_in[0];
    const float* source = (const float*)d_in[1];
    const float* cls_r_prob = (const float*)d_in[2];

    float* fused = (float*)d_out;
    float* src_out = fused + (size_t)Bn * Ln * Cn;

    char* w = (char*)d_ws;
    int* cls_idx = (int*)w;                                    // 92416 B
    size_t off = ((size_t)Bn * Ln * 4 + 1023) & ~(size_t)1023;
    float* bs = (float*)(w + off);                             // 16*23*1344*4 = 1978368 B

    hipLaunchKernelGGL(kB, dim3(Bn * NBn), dim3(512), 0, stream,
                       cls_pred, source, cls_r_prob, cls_idx, src_out, bs, fused);
    hipLaunchKernelGGL(kC, dim3(Bn * NBn), dim3(512), 0, stream,
                       cls_idx, cls_r_prob, bs, fused);
}